// Round 6
// baseline (147.876 us; speedup 1.0000x reference)
//
#include <hip/hip_runtime.h>
#include <hip/hip_bf16.h>
#include <stdint.h>

// ---------------------------------------------------------------------------
// MaskedPolicy: obs->MLP->heads (masked log-softmax, gather, entropy) + critic
// B=8192 OBS=512 HID=1024 N*SUM=2560 (+512 critic cols = 3072 fused GEMM3)
// G1/G2: 128x128 dbuf kernel (2 blocks/CU). G3: 256x256 BK64 8-phase kernel
// (fixed gates: vmcnt(8), 4+ phase flight on every stage).
// ---------------------------------------------------------------------------

typedef __bf16 v8bf __attribute__((ext_vector_type(8)));
typedef float  v4f  __attribute__((ext_vector_type(4)));

__device__ __forceinline__ void load_lds16(const void* g, void* l) {
  auto gp = (const __attribute__((address_space(1))) char*)(uintptr_t)g;
  auto lp = (__attribute__((address_space(3))) char*)(uintptr_t)l;
  __builtin_amdgcn_global_load_lds(gp, lp, 16, 0, 0);
}

#define BARRIER __builtin_amdgcn_s_barrier()
#define SCHEDB  __builtin_amdgcn_sched_barrier(0)
#define WAIT_LGKM0 do { asm volatile("s_waitcnt lgkmcnt(0)" ::: "memory"); SCHEDB; } while (0)
#define WAIT_LGKM8 do { asm volatile("s_waitcnt lgkmcnt(8)" ::: "memory"); SCHEDB; } while (0)
#define WAIT_VM8   do { asm volatile("s_waitcnt vmcnt(8)" ::: "memory"); SCHEDB; } while (0)
#define WAIT_VM0   do { asm volatile("s_waitcnt vmcnt(0)" ::: "memory"); SCHEDB; } while (0)

// ---------------------------------------------------------------------------
// prep kernels (unchanged, verified)
// ---------------------------------------------------------------------------

__global__ void convert_obs(const float4* __restrict__ in, int4* __restrict__ out, int n8) {
  const int i = blockIdx.x * blockDim.x + threadIdx.x;
  if (i >= n8) return;
  const float4 x = in[i * 2], y = in[i * 2 + 1];
  union { __hip_bfloat16 h[8]; int4 v; } u;
  u.h[0] = __float2bfloat16(x.x);
  u.h[1] = __float2bfloat16(x.y);
  u.h[2] = __float2bfloat16(x.z);
  u.h[3] = __float2bfloat16(x.w);
  u.h[4] = __float2bfloat16(y.x);
  u.h[5] = __float2bfloat16(y.y);
  u.h[6] = __float2bfloat16(y.z);
  u.h[7] = __float2bfloat16(y.w);
  out[i] = u.v;
}

__global__ void build_bias(const float* __restrict__ headsb, const float* __restrict__ bc1,
                           float* __restrict__ biasc) {
  const int i = blockIdx.x * blockDim.x + threadIdx.x;
  if (i < 2560) biasc[i] = headsb[i];
  else if (i < 3072) biasc[i] = bc1[i - 2560];
}

__global__ void transpose_to_bf16(const float* __restrict__ in, __hip_bfloat16* __restrict__ out,
                                  int R, int C) {
  __shared__ float t[32][33];
  const int bx = blockIdx.x * 32, by = blockIdx.y * 32;
  in  += (size_t)blockIdx.z * R * C;
  out += (size_t)blockIdx.z * R * C;
  const int x = threadIdx.x, y = threadIdx.y;
#pragma unroll
  for (int i = 0; i < 32; i += 8)
    t[y + i][x] = in[(size_t)(by + y + i) * C + bx + x];
  __syncthreads();
#pragma unroll
  for (int i = 0; i < 32; i += 8)
    out[(size_t)(bx + y + i) * R + by + x] = __float2bfloat16(t[x][y + i]);
}

// ---------------------------------------------------------------------------
// shared swizzle helpers (verified: pass + 0 bank conflicts)
// subtile = 16 rows x 64B; within 8KB region: row bits [9:6], slot bits [5:4],
// swizzle: byte ^= ((byte>>9)&1)<<5. Reader laneOff matches decode_chunk.
// ---------------------------------------------------------------------------

__device__ __forceinline__ void decode_chunk(int o, int& r, int& cb) {
  const int L = o ^ (((o >> 9) & 1) << 5);
  r  = ((L >> 10) << 4) | ((L >> 6) & 15);
  cb = ((L >> 4) & 3) << 4;
}

// ---------------------------------------------------------------------------
// G1/G2 GEMM: 128x128, BK=64, 4 waves, dbuf, 2 blocks/CU (round-4, verified)
// ---------------------------------------------------------------------------

__global__ __launch_bounds__(256, 2)
void gemm_db(const __hip_bfloat16* __restrict__ A,
             const __hip_bfloat16* __restrict__ Bt,
             const float* __restrict__ bias,
             __hip_bfloat16* __restrict__ C,
             int N, int K, int relu_from, int gx) {
  __shared__ char smem[65536];

  const int tid  = threadIdx.x;
  const int lane = tid & 63;
  const int wave = tid >> 6;
  const int wr = wave >> 1, wc = wave & 1;
  const int lr = lane & 15, ls = lane >> 4;

  const int nwg = gridDim.x;
  const int q8 = nwg >> 3;
  const int id = (blockIdx.x & 7) * q8 + (blockIdx.x >> 3);
  const int bx = id % gx, by = id / gx;
  const int m0 = by * 128, n0 = bx * 128;

  int r0, c0, r1, c1;
  decode_chunk(tid * 16, r0, c0);
  decode_chunk(tid * 16 + 4096, r1, c1);

  const size_t K2 = (size_t)K * 2;
  const char* pA0 = (const char*)A  + (size_t)(m0 + r0) * K2 + c0;
  const char* pA1 = (const char*)A  + (size_t)(m0 + r1) * K2 + c1;
  const char* pB0 = (const char*)Bt + (size_t)(n0 + r0) * K2 + c0;
  const char* pB1 = (const char*)Bt + (size_t)(n0 + r1) * K2 + c1;

  char* const s0 = smem + (tid << 4);

  auto stage = [&](int buf) {
    char* d = s0 + (buf << 15);
    load_lds16(pA0,      d);
    load_lds16(pA1,      d + 4096);
    load_lds16(pA0 + 64, d + 8192);
    load_lds16(pA1 + 64, d + 12288);
    load_lds16(pB0,      d + 16384);
    load_lds16(pB1,      d + 20480);
    load_lds16(pB0 + 64, d + 24576);
    load_lds16(pB1 + 64, d + 28672);
    pA0 += 128; pA1 += 128; pB0 += 128; pB1 += 128;
  };

  const int laneOff = lr * 64 + ((ls * 16) ^ ((lr & 8) << 2));

  v4f acc[4][4] = {};

  auto tile = [&](int buf, bool doStage, auto gate) {
    const char* aB = smem + (buf << 15) + wr * 4096 + laneOff;
    const char* bB = smem + (buf << 15) + 16384 + wc * 4096 + laneOff;
    v8bf a0[4], b0[4], a1[4], b1[4];
#pragma unroll
    for (int m = 0; m < 4; ++m) a0[m] = *(const v8bf*)(aB + m * 1024);
#pragma unroll
    for (int n = 0; n < 4; ++n) b0[n] = *(const v8bf*)(bB + n * 1024);
#pragma unroll
    for (int m = 0; m < 4; ++m) a1[m] = *(const v8bf*)(aB + 8192 + m * 1024);
#pragma unroll
    for (int n = 0; n < 4; ++n) b1[n] = *(const v8bf*)(bB + 8192 + n * 1024);
    WAIT_LGKM8;
    __builtin_amdgcn_s_setprio(1);
#pragma unroll
    for (int m = 0; m < 4; ++m)
#pragma unroll
      for (int n = 0; n < 4; ++n)
        acc[m][n] = __builtin_amdgcn_mfma_f32_16x16x32_bf16(a0[m], b0[n], acc[m][n], 0, 0, 0);
    __builtin_amdgcn_s_setprio(0); SCHEDB;
    WAIT_LGKM0;
    BARRIER;
    if (doStage) stage(buf);
    __builtin_amdgcn_s_setprio(1);
#pragma unroll
    for (int m = 0; m < 4; ++m)
#pragma unroll
      for (int n = 0; n < 4; ++n)
        acc[m][n] = __builtin_amdgcn_mfma_f32_16x16x32_bf16(a1[m], b1[n], acc[m][n], 0, 0, 0);
    __builtin_amdgcn_s_setprio(0); SCHEDB;
    gate();
    BARRIER;
  };

  stage(0);
  stage(1);
  WAIT_VM8;
  BARRIER; SCHEDB;

  const int NT = K >> 6;
  int t = 0;
  for (; t < NT - 2; ++t)
    tile(t & 1, true, [] { WAIT_VM8; });
  tile(t & 1, false, [] { WAIT_VM0; }); ++t;
  tile(t & 1, false, [] {});

  const int colb = n0 + wc * 64 + lr;
  const int rowb = m0 + wr * 64 + ls * 4;
#pragma unroll
  for (int n = 0; n < 4; ++n) {
    const int col = colb + n * 16;
    const float bv = bias[col];
    const bool rl = (col >= relu_from);
#pragma unroll
    for (int m = 0; m < 4; ++m) {
      const int rbase = rowb + m * 16;
#pragma unroll
      for (int j = 0; j < 4; ++j) {
        float v = acc[m][n][j] + bv;
        if (rl) v = fmaxf(v, 0.0f);
        C[(size_t)(rbase + j) * N + col] = __float2bfloat16(v);
      }
    }
  }
}

// ---------------------------------------------------------------------------
// G3 GEMM: 256x256, BK=64, 8 waves (2Mx4N), dbuf 128KiB, 8-phase.
// LDS per dbuf (64KB): A0ks0|A0ks1|A1ks0|A1ks1|B0ks0|B0ks1|B1ks0|B1ks1 (8KB ea)
// Stage slots: p3 = B-pair of tile+2, p4 = A-pair, p7/p8 mirror.
// Gates: vmcnt(8) after p4/p8 MFMA (all stages get >= 4-phase flight).
// ---------------------------------------------------------------------------

template<int M0, int N0>
__device__ __forceinline__ void q16(v4f (&acc)[8][4], const v8bf (&aF)[4][2],
                                    const v8bf (&bF)[4][2]) {
#pragma unroll
  for (int m = 0; m < 4; ++m)
#pragma unroll
    for (int n = 0; n < 2; ++n)
#pragma unroll
      for (int ks = 0; ks < 2; ++ks)
        acc[M0 + m][N0 + n] = __builtin_amdgcn_mfma_f32_16x16x32_bf16(
            aF[m][ks], bF[N0 + n][ks], acc[M0 + m][N0 + n], 0, 0, 0);
}

__global__ __launch_bounds__(512, 2)
void gemm_256(const __hip_bfloat16* __restrict__ A,
              const __hip_bfloat16* __restrict__ Bt,
              const float* __restrict__ bias,
              __hip_bfloat16* __restrict__ C,
              int N, int K, int relu_from, int gx) {
  __shared__ char smem[131072];

  const int tid  = threadIdx.x;
  const int lane = tid & 63;
  const int wave = tid >> 6;
  const int wr = wave >> 2;   // 0..1
  const int wc = wave & 3;    // 0..3
  const int lr = lane & 15, ls = lane >> 4;

  const int nwg = gridDim.x;
  const int q8 = nwg >> 3;
  const int id = (blockIdx.x & 7) * q8 + (blockIdx.x >> 3);
  const int bx = id % gx, by = id / gx;
  const int m0 = by * 256, n0 = bx * 256;

  int r0, c0;
  decode_chunk(tid * 16, r0, c0);   // one chunk per thread per 8KB region

  const size_t K2 = (size_t)K * 2;
  const char* pA0 = (const char*)A  + (size_t)(m0 +       r0) * K2 + c0;
  const char* pA1 = (const char*)A  + (size_t)(m0 + 128 + r0) * K2 + c0;
  const char* pB0 = (const char*)Bt + (size_t)(n0 +       r0) * K2 + c0;
  const char* pB1 = (const char*)Bt + (size_t)(n0 + 128 + r0) * K2 + c0;

  char* const s0 = smem + (tid << 4);

  auto stA = [&](int db) {            // 4 loads: A0ks0,A0ks1,A1ks0,A1ks1
    char* d = s0 + (db << 16);
    load_lds16(pA0,      d);
    load_lds16(pA0 + 64, d + 8192);
    load_lds16(pA1,      d + 16384);
    load_lds16(pA1 + 64, d + 24576);
    pA0 += 128; pA1 += 128;
  };
  auto stB = [&](int db) {            // 4 loads: B0ks0,B0ks1,B1ks0,B1ks1
    char* d = s0 + (db << 16) + 32768;
    load_lds16(pB0,      d);
    load_lds16(pB0 + 64, d + 8192);
    load_lds16(pB1,      d + 16384);
    load_lds16(pB1 + 64, d + 24576);
    pB0 += 128; pB1 += 128;
  };

  const int laneOff = lr * 64 + ((ls * 16) ^ ((lr & 8) << 2));

  v4f acc[8][4] = {};

  // one K64 tile = 4 phases; gateMode: 0 = vmcnt(8), 1 = vmcnt(0), 2 = none
  auto ktile = [&](int db, bool doStage, int gateMode) {
    const char* aB = smem + (db << 16) + wr * 16384 + laneOff;
    const char* bB = smem + (db << 16) + 32768 + (wc >> 1) * 16384 + (wc & 1) * 4096 + laneOff;
    v8bf aF[4][2], bF[4][2];
    // p1: read aLo + all B, MFMA quadrant <0,0>
#pragma unroll
    for (int m = 0; m < 4; ++m)
#pragma unroll
      for (int ks = 0; ks < 2; ++ks) aF[m][ks] = *(const v8bf*)(aB + ks * 8192 + m * 1024);
#pragma unroll
    for (int n = 0; n < 4; ++n)
#pragma unroll
      for (int ks = 0; ks < 2; ++ks) bF[n][ks] = *(const v8bf*)(bB + ks * 8192 + n * 1024);
    BARRIER; WAIT_LGKM0;
    __builtin_amdgcn_s_setprio(1); q16<0, 0>(acc, aF, bF); __builtin_amdgcn_s_setprio(0); SCHEDB;
    BARRIER;
    // p2: MFMA quadrant <0,2> (all inputs already resident)
    __builtin_amdgcn_s_setprio(1); q16<0, 2>(acc, aF, bF); __builtin_amdgcn_s_setprio(0); SCHEDB;
    BARRIER;
    // p3: read aHi; stage B-pair of tile+2 (db.B free: last read was p1)
#pragma unroll
    for (int m = 0; m < 4; ++m)
#pragma unroll
      for (int ks = 0; ks < 2; ++ks) aF[m][ks] = *(const v8bf*)(aB + ks * 8192 + (4 + m) * 1024);
    if (doStage) stB(db);
    BARRIER; WAIT_LGKM0;
    __builtin_amdgcn_s_setprio(1); q16<4, 2>(acc, aF, bF); __builtin_amdgcn_s_setprio(0); SCHEDB;
    BARRIER;
    // p4: stage A-pair of tile+2 (db.A free: last read was p3); MFMA <4,0>; gate
    if (doStage) stA(db);
    BARRIER;
    __builtin_amdgcn_s_setprio(1); q16<4, 0>(acc, aF, bF); __builtin_amdgcn_s_setprio(0); SCHEDB;
    if (gateMode == 0) { WAIT_VM8; }
    else if (gateMode == 1) { WAIT_VM0; }
    BARRIER;
  };

  // prologue: stage tiles 0 (db0) and 1 (db1); tile0 resident, tile1 in flight
  stA(0); stB(0);
  stA(1); stB(1);
  WAIT_VM8;
  BARRIER; SCHEDB;

  const int NP = K >> 7;   // pairs of K64 tiles (K % 128 == 0, NP >= 2)
  for (int i = 0; i < NP - 1; ++i) {
    ktile(0, true, 0);
    ktile(1, true, 0);
  }
  ktile(0, false, 1);
  ktile(1, false, 2);

  // epilogue: C/D layout col=lane&15, row=(lane>>4)*4+reg  [m89-verified]
  const int colb = n0 + wc * 64 + lr;
  const int rowb = m0 + wr * 128 + ls * 4;
#pragma unroll
  for (int n = 0; n < 4; ++n) {
    const int col = colb + n * 16;
    const float bv = bias[col];
    const bool rl = (col >= relu_from);
#pragma unroll
    for (int m = 0; m < 8; ++m) {
      const int rbase = rowb + m * 16;
#pragma unroll
      for (int j = 0; j < 4; ++j) {
        float v = acc[m][n][j] + bv;
        if (rl) v = fmaxf(v, 0.0f);
        C[(size_t)(rbase + j) * N + col] = __float2bfloat16(v);
      }
    }
  }
}

// ---------------------------------------------------------------------------
// finalize (unchanged, verified): wave per row, 8 segments/pass, vector loads
// ---------------------------------------------------------------------------

__global__ __launch_bounds__(256)
void finalize_kernel(const __hip_bfloat16* __restrict__ out3,
                     const int* __restrict__ masks,
                     const int* __restrict__ actions,
                     const float* __restrict__ Wc2,
                     const float* __restrict__ bc2,
                     float* __restrict__ out) {
  const int lane = threadIdx.x & 63;
  const int r = blockIdx.x * 4 + (threadIdx.x >> 6);
  const __hip_bfloat16* row = out3 + (size_t)r * 3072;
  const int* mrow = masks + (size_t)r * 2560;
  const int* arow = actions + r * 40;

  const int g = lane >> 3;

  float lp_sum = 0.f, ent_sum = 0.f;

#pragma unroll
  for (int p = 0; p < 5; ++p) {
    const int base = p * 512 + lane * 8;
    union { int4 q; __hip_bfloat16 h[8]; } u;
    u.q = *(const int4*)(row + base);
    const int4 ma = *(const int4*)(mrow + base);
    const int4 mb = *(const int4*)(mrow + base + 4);

    float v[8];
    v[0] = ma.x ? __bfloat162float(u.h[0]) : -1.0e9f;
    v[1] = ma.y ? __bfloat162float(u.h[1]) : -1.0e9f;
    v[2] = ma.z ? __bfloat162float(u.h[2]) : -1.0e9f;
    v[3] = ma.w ? __bfloat162float(u.h[3]) : -1.0e9f;
    v[4] = mb.x ? __bfloat162float(u.h[4]) : -1.0e9f;
    v[5] = mb.y ? __bfloat162float(u.h[5]) : -1.0e9f;
    v[6] = mb.z ? __bfloat162float(u.h[6]) : -1.0e9f;
    v[7] = mb.w ? __bfloat162float(u.h[7]) : -1.0e9f;

    float mx = fmaxf(fmaxf(fmaxf(v[0], v[1]), fmaxf(v[2], v[3])),
                     fmaxf(fmaxf(v[4], v[5]), fmaxf(v[6], v[7])));
#pragma unroll
    for (int o = 1; o < 8; o <<= 1) mx = fmaxf(mx, __shfl_xor(mx, o));

    float s = 0.f, sv = 0.f;
#pragma unroll
    for (int j = 0; j < 8; ++j) {
      const float e = __expf(v[j] - mx);
      s += e;
      sv += e * v[j];
    }
#pragma unroll
    for (int o = 1; o < 8; o <<= 1) { s += __shfl_xor(s, o); sv += __shfl_xor(sv, o); }

    const float logZ = __logf(s) + mx;

    const int act = arow[p * 8 + g];
    float va_loc = v[0];
#pragma unroll
    for (int j = 1; j < 8; ++j) va_loc = ((act & 7) == j) ? v[j] : va_loc;
    const float va = __shfl(va_loc, (lane & 56) | ((act >> 3) & 7));

    if ((unsigned)act < 64u) {
      lp_sum += va - logZ;
      ent_sum += logZ - sv / s;
    } else {
      lp_sum += -1000.0f;
    }
  }

#pragma unroll
  for (int o = 8; o < 64; o <<= 1) {
    lp_sum += __shfl_xor(lp_sum, o);
    ent_sum += __shfl_xor(ent_sum, o);
  }

  union { int4 q; __hip_bfloat16 h[8]; } c;
  c.q = *(const int4*)(row + 2560 + lane * 8);
  const float4 w0 = *(const float4*)(Wc2 + lane * 8);
  const float4 w1 = *(const float4*)(Wc2 + lane * 8 + 4);
  float acc = __bfloat162float(c.h[0]) * w0.x + __bfloat162float(c.h[1]) * w0.y +
              __bfloat162float(c.h[2]) * w0.z + __bfloat162float(c.h[3]) * w0.w +
              __bfloat162float(c.h[4]) * w1.x + __bfloat162float(c.h[5]) * w1.y +
              __bfloat162float(c.h[6]) * w1.z + __bfloat162float(c.h[7]) * w1.w;
#pragma unroll
  for (int o = 32; o > 0; o >>= 1) acc += __shfl_xor(acc, o);

  if (lane == 0) {
    out[r]         = lp_sum;
    out[8192 + r]  = ent_sum;
    out[16384 + r] = acc + bc2[0];
  }
}

// ---------------------------------------------------------------------------

extern "C" void kernel_launch(void* const* d_in, const int* in_sizes, int n_in,
                              void* d_out, int out_size, void* d_ws, size_t ws_size,
                              hipStream_t stream) {
  const float* obs    = (const float*)d_in[0];
  const int*   actions= (const int*)d_in[1];
  const int*   masks  = (const int*)d_in[2];
  const float* W1     = (const float*)d_in[3];
  const float* b1     = (const float*)d_in[4];
  const float* W2     = (const float*)d_in[5];
  const float* b2     = (const float*)d_in[6];
  const float* headsW = (const float*)d_in[7];
  const float* headsb = (const float*)d_in[8];
  const float* Wc1    = (const float*)d_in[9];
  const float* bc1    = (const float*)d_in[10];
  const float* Wc2    = (const float*)d_in[11];
  const float* bc2    = (const float*)d_in[12];
  float* out = (float*)d_out;

  char* ws = (char*)d_ws;
  __hip_bfloat16* obsB  = (__hip_bfloat16*)(ws);              // 8192*512*2   = 8388608
  __hip_bfloat16* W1t   = (__hip_bfloat16*)(ws + 8388608);    // 1024*512*2   = 1048576
  __hip_bfloat16* W2t   = (__hip_bfloat16*)(ws + 9437184);    // 1024*1024*2  = 2097152
  __hip_bfloat16* Wbigt = (__hip_bfloat16*)(ws + 11534336);   // 3072*1024*2  = 6291456
  float*          biasc = (float*)(ws + 17825792);            // 3072*4       = 12288
  __hip_bfloat16* h1    = (__hip_bfloat16*)(ws + 17838080);   // 8192*1024*2  = 16777216
  __hip_bfloat16* h2    = (__hip_bfloat16*)(ws + 34615296);   // 8192*1024*2  = 16777216
  __hip_bfloat16* out3  = (__hip_bfloat16*)(ws + 51392512);   // 8192*3072*2  = 50331648

  convert_obs<<<2048, 256, 0, stream>>>((const float4*)obs, (int4*)obsB, 524288);
  build_bias<<<12, 256, 0, stream>>>(headsb, bc1, biasc);
  transpose_to_bf16<<<dim3(32, 16, 1), dim3(32, 8), 0, stream>>>(W1, W1t, 512, 1024);
  transpose_to_bf16<<<dim3(32, 32, 1), dim3(32, 8), 0, stream>>>(W2, W2t, 1024, 1024);
  transpose_to_bf16<<<dim3(10, 32, 8), dim3(32, 8), 0, stream>>>(headsW, Wbigt, 1024, 320);
  transpose_to_bf16<<<dim3(16, 32, 1), dim3(32, 8), 0, stream>>>(Wc1, Wbigt + 2560 * 1024, 1024, 512);

  // G1/G2: 128x128 dbuf, 2 blocks/CU (512 blocks = 1 full CU-wave x2)
  gemm_db<<<dim3(512), 256, 0, stream>>>(obsB, W1t, b1, h1, 1024, 512, 0, 8);
  gemm_db<<<dim3(512), 256, 0, stream>>>(h1, W2t, b2, h2, 1024, 1024, 0, 8);
  // G3: 256x256 8-phase (32x12 = 384 blocks)
  gemm_256<<<dim3(384), 512, 0, stream>>>(h2, Wbigt, biasc, out3, 3072, 1024, 2560, 12);

  finalize_kernel<<<2048, 256, 0, stream>>>(out3, masks, actions, Wc2, bc2, out);
}

// Round 7
// 142.080 us; speedup vs baseline: 1.0408x; 1.0408x over previous
//
#include <hip/hip_runtime.h>
#include <hip/hip_bf16.h>
#include <stdint.h>

// ---------------------------------------------------------------------------
// MaskedPolicy: obs->MLP->heads (masked log-softmax, gather, entropy) + critic
// B=8192 OBS=512 HID=1024 N*SUM=2560 (+512 critic cols = 3072 fused GEMM3)
// G1/G2: 128x128 dbuf GEMM (2 blocks/CU, verified 805 TF class).
// G3: same GEMM structure + FUSED masked-softmax epilogue (f32, in-register)
//     -> writes 2.6MB partials + 8MB critic instead of 50MB logits.
// ---------------------------------------------------------------------------

typedef __bf16 v8bf __attribute__((ext_vector_type(8)));
typedef float  v4f  __attribute__((ext_vector_type(4)));

__device__ __forceinline__ void load_lds16(const void* g, void* l) {
  auto gp = (const __attribute__((address_space(1))) char*)(uintptr_t)g;
  auto lp = (__attribute__((address_space(3))) char*)(uintptr_t)l;
  __builtin_amdgcn_global_load_lds(gp, lp, 16, 0, 0);
}

#define BARRIER __builtin_amdgcn_s_barrier()
#define SCHEDB  __builtin_amdgcn_sched_barrier(0)
#define WAIT_LGKM0 do { asm volatile("s_waitcnt lgkmcnt(0)" ::: "memory"); SCHEDB; } while (0)
#define WAIT_LGKM8 do { asm volatile("s_waitcnt lgkmcnt(8)" ::: "memory"); SCHEDB; } while (0)
#define WAIT_VM8   do { asm volatile("s_waitcnt vmcnt(8)" ::: "memory"); SCHEDB; } while (0)
#define WAIT_VM0   do { asm volatile("s_waitcnt vmcnt(0)" ::: "memory"); SCHEDB; } while (0)

// ---------------------------------------------------------------------------
// prep mega-kernel: all weight transposes + obs conversion + bias concat
// block ranges: [0,512) W1t | [512,1536) W2t | [1536,4096) headsW |
// [4096,4608) Wc1 | [4608,6656) obs | [6656,6668) bias
// ---------------------------------------------------------------------------

__global__ __launch_bounds__(256)
void prep_kernel(const float* __restrict__ obs,
                 const float* __restrict__ W1, const float* __restrict__ W2,
                 const float* __restrict__ headsW, const float* __restrict__ Wc1,
                 const float* __restrict__ headsb, const float* __restrict__ bc1,
                 int4* __restrict__ obsB,
                 __hip_bfloat16* __restrict__ W1t, __hip_bfloat16* __restrict__ W2t,
                 __hip_bfloat16* __restrict__ Wbigt, float* __restrict__ biasc) {
  const int b = blockIdx.x;
  const int tid = threadIdx.x;
  if (b < 4608) {
    const float* in; __hip_bfloat16* outp; int R, C, bxx, byy;
    if (b < 512)       { in = W1;  outp = W1t; R = 512;  C = 1024; bxx = b % 32; byy = b / 32; }
    else if (b < 1536) { int i = b - 512;  in = W2;  outp = W2t; R = 1024; C = 1024; bxx = i % 32; byy = i / 32; }
    else if (b < 4096) { int i = b - 1536; int bz = i / 320; i %= 320;
                         in = headsW + (size_t)bz * 1024 * 320;
                         outp = Wbigt + (size_t)bz * 320 * 1024;
                         R = 1024; C = 320; bxx = i % 10; byy = i / 10; }
    else               { int i = b - 4096; in = Wc1; outp = Wbigt + 2560 * 1024;
                         R = 1024; C = 512; bxx = i % 16; byy = i / 16; }
    __shared__ float t[32][33];
    const int x = tid & 31, y = tid >> 5;
    const int bx0 = bxx * 32, by0 = byy * 32;
#pragma unroll
    for (int i = 0; i < 32; i += 8)
      t[y + i][x] = in[(size_t)(by0 + y + i) * C + bx0 + x];
    __syncthreads();
#pragma unroll
    for (int i = 0; i < 32; i += 8)
      outp[(size_t)(bx0 + y + i) * R + by0 + x] = __float2bfloat16(t[x][y + i]);
  } else if (b < 6656) {
    const int i = (b - 4608) * 256 + tid;   // < 524288
    const float4 x = ((const float4*)obs)[i * 2], y = ((const float4*)obs)[i * 2 + 1];
    union { __hip_bfloat16 h[8]; int4 v; } u;
    u.h[0] = __float2bfloat16(x.x); u.h[1] = __float2bfloat16(x.y);
    u.h[2] = __float2bfloat16(x.z); u.h[3] = __float2bfloat16(x.w);
    u.h[4] = __float2bfloat16(y.x); u.h[5] = __float2bfloat16(y.y);
    u.h[6] = __float2bfloat16(y.z); u.h[7] = __float2bfloat16(y.w);
    obsB[i] = u.v;
  } else {
    const int i = (b - 6656) * 256 + tid;
    if (i < 2560) biasc[i] = headsb[i];
    else if (i < 3072) biasc[i] = bc1[i - 2560];
  }
}

// ---------------------------------------------------------------------------
// shared swizzle helpers (verified: pass + 0 bank conflicts)
// ---------------------------------------------------------------------------

__device__ __forceinline__ void decode_chunk(int o, int& r, int& cb) {
  const int L = o ^ (((o >> 9) & 1) << 5);
  r  = ((L >> 10) << 4) | ((L >> 6) & 15);
  cb = ((L >> 4) & 3) << 4;
}

// ---------------------------------------------------------------------------
// G1/G2 GEMM: 128x128, BK=64, 4 waves, dbuf, 2 blocks/CU (round-4, verified)
// ---------------------------------------------------------------------------

__global__ __launch_bounds__(256, 2)
void gemm_db(const __hip_bfloat16* __restrict__ A,
             const __hip_bfloat16* __restrict__ Bt,
             const float* __restrict__ bias,
             __hip_bfloat16* __restrict__ C,
             int N, int K, int relu_from, int gx) {
  __shared__ char smem[65536];

  const int tid  = threadIdx.x;
  const int lane = tid & 63;
  const int wave = tid >> 6;
  const int wr = wave >> 1, wc = wave & 1;
  const int lr = lane & 15, ls = lane >> 4;

  const int nwg = gridDim.x;
  const int q8 = nwg >> 3;
  const int id = (blockIdx.x & 7) * q8 + (blockIdx.x >> 3);
  const int bx = id % gx, by = id / gx;
  const int m0 = by * 128, n0 = bx * 128;

  int r0, c0, r1, c1;
  decode_chunk(tid * 16, r0, c0);
  decode_chunk(tid * 16 + 4096, r1, c1);

  const size_t K2 = (size_t)K * 2;
  const char* pA0 = (const char*)A  + (size_t)(m0 + r0) * K2 + c0;
  const char* pA1 = (const char*)A  + (size_t)(m0 + r1) * K2 + c1;
  const char* pB0 = (const char*)Bt + (size_t)(n0 + r0) * K2 + c0;
  const char* pB1 = (const char*)Bt + (size_t)(n0 + r1) * K2 + c1;

  char* const s0 = smem + (tid << 4);

  auto stage = [&](int buf) {
    char* d = s0 + (buf << 15);
    load_lds16(pA0,      d);
    load_lds16(pA1,      d + 4096);
    load_lds16(pA0 + 64, d + 8192);
    load_lds16(pA1 + 64, d + 12288);
    load_lds16(pB0,      d + 16384);
    load_lds16(pB1,      d + 20480);
    load_lds16(pB0 + 64, d + 24576);
    load_lds16(pB1 + 64, d + 28672);
    pA0 += 128; pA1 += 128; pB0 += 128; pB1 += 128;
  };

  const int laneOff = lr * 64 + ((ls * 16) ^ ((lr & 8) << 2));

  v4f acc[4][4] = {};

  auto tile = [&](int buf, bool doStage, auto gate) {
    const char* aB = smem + (buf << 15) + wr * 4096 + laneOff;
    const char* bB = smem + (buf << 15) + 16384 + wc * 4096 + laneOff;
    v8bf a0[4], b0[4], a1[4], b1[4];
#pragma unroll
    for (int m = 0; m < 4; ++m) a0[m] = *(const v8bf*)(aB + m * 1024);
#pragma unroll
    for (int n = 0; n < 4; ++n) b0[n] = *(const v8bf*)(bB + n * 1024);
#pragma unroll
    for (int m = 0; m < 4; ++m) a1[m] = *(const v8bf*)(aB + 8192 + m * 1024);
#pragma unroll
    for (int n = 0; n < 4; ++n) b1[n] = *(const v8bf*)(bB + 8192 + n * 1024);
    WAIT_LGKM8;
    __builtin_amdgcn_s_setprio(1);
#pragma unroll
    for (int m = 0; m < 4; ++m)
#pragma unroll
      for (int n = 0; n < 4; ++n)
        acc[m][n] = __builtin_amdgcn_mfma_f32_16x16x32_bf16(a0[m], b0[n], acc[m][n], 0, 0, 0);
    __builtin_amdgcn_s_setprio(0); SCHEDB;
    WAIT_LGKM0;
    BARRIER;
    if (doStage) stage(buf);
    __builtin_amdgcn_s_setprio(1);
#pragma unroll
    for (int m = 0; m < 4; ++m)
#pragma unroll
      for (int n = 0; n < 4; ++n)
        acc[m][n] = __builtin_amdgcn_mfma_f32_16x16x32_bf16(a1[m], b1[n], acc[m][n], 0, 0, 0);
    __builtin_amdgcn_s_setprio(0); SCHEDB;
    gate();
    BARRIER;
  };

  stage(0);
  stage(1);
  WAIT_VM8;
  BARRIER; SCHEDB;

  const int NT = K >> 6;
  int t = 0;
  for (; t < NT - 2; ++t)
    tile(t & 1, true, [] { WAIT_VM8; });
  tile(t & 1, false, [] { WAIT_VM0; }); ++t;
  tile(t & 1, false, [] {});

  const int colb = n0 + wc * 64 + lr;
  const int rowb = m0 + wr * 64 + ls * 4;
#pragma unroll
  for (int n = 0; n < 4; ++n) {
    const int col = colb + n * 16;
    const float bv = bias[col];
    const bool rl = (col >= relu_from);
#pragma unroll
    for (int m = 0; m < 4; ++m) {
      const int rbase = rowb + m * 16;
#pragma unroll
      for (int j = 0; j < 4; ++j) {
        float v = acc[m][n][j] + bv;
        if (rl) v = fmaxf(v, 0.0f);
        C[(size_t)(rbase + j) * N + col] = __float2bfloat16(v);
      }
    }
  }
}

// ---------------------------------------------------------------------------
// G3 fused: same GEMM core; epilogue computes masked log-softmax per segment
// in f32 (one wave = one 64-col segment x 64 rows; each 16-lane group holds a
// full row), writes {lp, ent} partials. Critic tiles (bx>=20) write bf16.
// Grid 24x64 = 1536 (gx=24). K = 1024.
// ---------------------------------------------------------------------------

__global__ __launch_bounds__(256, 2)
void gemm_fused(const __hip_bfloat16* __restrict__ A,
                const __hip_bfloat16* __restrict__ Bt,
                const float* __restrict__ bias,
                const int* __restrict__ masks,
                const int* __restrict__ actions,
                float2* __restrict__ partials,
                __hip_bfloat16* __restrict__ critic,
                int K) {
  __shared__ char smem[65536];

  const int tid  = threadIdx.x;
  const int lane = tid & 63;
  const int wave = tid >> 6;
  const int wr = wave >> 1, wc = wave & 1;
  const int lr = lane & 15, ls = lane >> 4;

  const int nwg = gridDim.x;
  const int q8 = nwg >> 3;
  const int id = (blockIdx.x & 7) * q8 + (blockIdx.x >> 3);
  const int bx = id % 24, by = id / 24;
  const int m0 = by * 128, n0 = bx * 128;

  int r0, c0, r1, c1;
  decode_chunk(tid * 16, r0, c0);
  decode_chunk(tid * 16 + 4096, r1, c1);

  const size_t K2 = (size_t)K * 2;
  const char* pA0 = (const char*)A  + (size_t)(m0 + r0) * K2 + c0;
  const char* pA1 = (const char*)A  + (size_t)(m0 + r1) * K2 + c1;
  const char* pB0 = (const char*)Bt + (size_t)(n0 + r0) * K2 + c0;
  const char* pB1 = (const char*)Bt + (size_t)(n0 + r1) * K2 + c1;

  char* const s0 = smem + (tid << 4);

  auto stage = [&](int buf) {
    char* d = s0 + (buf << 15);
    load_lds16(pA0,      d);
    load_lds16(pA1,      d + 4096);
    load_lds16(pA0 + 64, d + 8192);
    load_lds16(pA1 + 64, d + 12288);
    load_lds16(pB0,      d + 16384);
    load_lds16(pB1,      d + 20480);
    load_lds16(pB0 + 64, d + 24576);
    load_lds16(pB1 + 64, d + 28672);
    pA0 += 128; pA1 += 128; pB0 += 128; pB1 += 128;
  };

  const int laneOff = lr * 64 + ((ls * 16) ^ ((lr & 8) << 2));

  v4f acc[4][4] = {};

  auto tile = [&](int buf, bool doStage, auto gate) {
    const char* aB = smem + (buf << 15) + wr * 4096 + laneOff;
    const char* bB = smem + (buf << 15) + 16384 + wc * 4096 + laneOff;
    v8bf a0[4], b0[4], a1[4], b1[4];
#pragma unroll
    for (int m = 0; m < 4; ++m) a0[m] = *(const v8bf*)(aB + m * 1024);
#pragma unroll
    for (int n = 0; n < 4; ++n) b0[n] = *(const v8bf*)(bB + n * 1024);
#pragma unroll
    for (int m = 0; m < 4; ++m) a1[m] = *(const v8bf*)(aB + 8192 + m * 1024);
#pragma unroll
    for (int n = 0; n < 4; ++n) b1[n] = *(const v8bf*)(bB + 8192 + n * 1024);
    WAIT_LGKM8;
    __builtin_amdgcn_s_setprio(1);
#pragma unroll
    for (int m = 0; m < 4; ++m)
#pragma unroll
      for (int n = 0; n < 4; ++n)
        acc[m][n] = __builtin_amdgcn_mfma_f32_16x16x32_bf16(a0[m], b0[n], acc[m][n], 0, 0, 0);
    __builtin_amdgcn_s_setprio(0); SCHEDB;
    WAIT_LGKM0;
    BARRIER;
    if (doStage) stage(buf);
    __builtin_amdgcn_s_setprio(1);
#pragma unroll
    for (int m = 0; m < 4; ++m)
#pragma unroll
      for (int n = 0; n < 4; ++n)
        acc[m][n] = __builtin_amdgcn_mfma_f32_16x16x32_bf16(a1[m], b1[n], acc[m][n], 0, 0, 0);
    __builtin_amdgcn_s_setprio(0); SCHEDB;
    gate();
    BARRIER;
  };

  stage(0);
  stage(1);
  WAIT_VM8;
  BARRIER; SCHEDB;

  const int NT = K >> 6;
  int t = 0;
  for (; t < NT - 2; ++t)
    tile(t & 1, true, [] { WAIT_VM8; });
  tile(t & 1, false, [] { WAIT_VM0; }); ++t;
  tile(t & 1, false, [] {});

  const int rowb = m0 + wr * 64 + ls * 4;

  if (bx < 20) {
    // ---- fused masked log-softmax for this wave's segment ----
    const int seg = bx * 2 + wc;
    float bv[4];
#pragma unroll
    for (int n = 0; n < 4; ++n) bv[n] = bias[n0 + wc * 64 + n * 16 + lr];
#pragma unroll
    for (int m = 0; m < 4; ++m) {
#pragma unroll
      for (int j = 0; j < 4; ++j) {
        const int row = rowb + m * 16 + j;
        const int* mrow = masks + (size_t)row * 2560 + seg * 64 + lr;
        float v[4];
#pragma unroll
        for (int n = 0; n < 4; ++n) {
          const int mk = mrow[n * 16];
          v[n] = mk ? (acc[m][n][j] + bv[n]) : -1.0e9f;
        }
        float mx = fmaxf(fmaxf(v[0], v[1]), fmaxf(v[2], v[3]));
#pragma unroll
        for (int o = 1; o < 16; o <<= 1) mx = fmaxf(mx, __shfl_xor(mx, o));
        float s = 0.f, sv = 0.f;
#pragma unroll
        for (int n = 0; n < 4; ++n) {
          const float e = __expf(v[n] - mx);
          s += e; sv += e * v[n];
        }
#pragma unroll
        for (int o = 1; o < 16; o <<= 1) { s += __shfl_xor(s, o); sv += __shfl_xor(sv, o); }
        const float logZ = __logf(s) + mx;
        const int act = actions[row * 40 + seg];
        float va_loc = v[0];
        va_loc = (((act >> 4) & 3) == 1) ? v[1] : va_loc;
        va_loc = (((act >> 4) & 3) == 2) ? v[2] : va_loc;
        va_loc = (((act >> 4) & 3) == 3) ? v[3] : va_loc;
        const float va = __shfl(va_loc, (lane & 48) | (act & 15));
        float lp, ent;
        if ((unsigned)act < 64u) { lp = va - logZ; ent = logZ - sv / s; }
        else                     { lp = -1000.0f;  ent = 0.0f; }
        if (lr == 0) partials[row * 40 + seg] = make_float2(lp, ent);
      }
    }
  } else {
    // ---- critic columns: relu + bf16 store to compact [8192][512] ----
    const int cb = (bx - 20) * 128 + wc * 64;
#pragma unroll
    for (int n = 0; n < 4; ++n) {
      const int col = cb + n * 16 + lr;
      const float bvv = bias[2560 + col];
#pragma unroll
      for (int m = 0; m < 4; ++m) {
        const int rbase = rowb + m * 16;
#pragma unroll
        for (int j = 0; j < 4; ++j)
          critic[(size_t)(rbase + j) * 512 + col] =
              __float2bfloat16(fmaxf(acc[m][n][j] + bvv, 0.0f));
      }
    }
  }
}

// ---------------------------------------------------------------------------
// finalize v3: tiny reduce — 80 f32 partials + critic dot per row
// ---------------------------------------------------------------------------

__global__ __launch_bounds__(256)
void finalize3(const float2* __restrict__ partials,
               const __hip_bfloat16* __restrict__ critic,
               const float* __restrict__ Wc2,
               const float* __restrict__ bc2,
               float* __restrict__ out) {
  const int lane = threadIdx.x & 63;
  const int r = blockIdx.x * 4 + (threadIdx.x >> 6);

  float lp = 0.f, ent = 0.f;
  if (lane < 40) {
    const float2 t = partials[r * 40 + lane];
    lp = t.x; ent = t.y;
  }
#pragma unroll
  for (int o = 32; o > 0; o >>= 1) { lp += __shfl_xor(lp, o); ent += __shfl_xor(ent, o); }

  union { int4 q; __hip_bfloat16 h[8]; } c;
  c.q = *(const int4*)(critic + (size_t)r * 512 + lane * 8);
  const float4 w0 = *(const float4*)(Wc2 + lane * 8);
  const float4 w1 = *(const float4*)(Wc2 + lane * 8 + 4);
  float acc = __bfloat162float(c.h[0]) * w0.x + __bfloat162float(c.h[1]) * w0.y +
              __bfloat162float(c.h[2]) * w0.z + __bfloat162float(c.h[3]) * w0.w +
              __bfloat162float(c.h[4]) * w1.x + __bfloat162float(c.h[5]) * w1.y +
              __bfloat162float(c.h[6]) * w1.z + __bfloat162float(c.h[7]) * w1.w;
#pragma unroll
  for (int o = 32; o > 0; o >>= 1) acc += __shfl_xor(acc, o);

  if (lane == 0) {
    out[r]         = lp;
    out[8192 + r]  = ent;
    out[16384 + r] = acc + bc2[0];
  }
}

// ---------------------------------------------------------------------------

extern "C" void kernel_launch(void* const* d_in, const int* in_sizes, int n_in,
                              void* d_out, int out_size, void* d_ws, size_t ws_size,
                              hipStream_t stream) {
  const float* obs    = (const float*)d_in[0];
  const int*   actions= (const int*)d_in[1];
  const int*   masks  = (const int*)d_in[2];
  const float* W1     = (const float*)d_in[3];
  const float* b1     = (const float*)d_in[4];
  const float* W2     = (const float*)d_in[5];
  const float* b2     = (const float*)d_in[6];
  const float* headsW = (const float*)d_in[7];
  const float* headsb = (const float*)d_in[8];
  const float* Wc1    = (const float*)d_in[9];
  const float* bc1    = (const float*)d_in[10];
  const float* Wc2    = (const float*)d_in[11];
  const float* bc2    = (const float*)d_in[12];
  float* out = (float*)d_out;

  char* ws = (char*)d_ws;
  __hip_bfloat16* obsB  = (__hip_bfloat16*)(ws);              // 8192*512*2   = 8388608
  __hip_bfloat16* W1t   = (__hip_bfloat16*)(ws + 8388608);    // 1024*512*2   = 1048576
  __hip_bfloat16* W2t   = (__hip_bfloat16*)(ws + 9437184);    // 1024*1024*2  = 2097152
  __hip_bfloat16* Wbigt = (__hip_bfloat16*)(ws + 11534336);   // 3072*1024*2  = 6291456
  float*          biasc = (float*)(ws + 17825792);            // 3072*4       = 12288
  __hip_bfloat16* h1    = (__hip_bfloat16*)(ws + 17838080);   // 8192*1024*2  = 16777216
  __hip_bfloat16* h2    = (__hip_bfloat16*)(ws + 34615296);   // 8192*1024*2  = 16777216
  float2*      partials = (float2*)(ws + 51392512);           // 8192*40*8    = 2621440
  __hip_bfloat16* critic= (__hip_bfloat16*)(ws + 54013952);   // 8192*512*2   = 8388608
  // total ws use: 62,402,560 bytes

  prep_kernel<<<6668, 256, 0, stream>>>(obs, W1, W2, headsW, Wc1, headsb, bc1,
                                        (int4*)obsB, W1t, W2t, Wbigt, biasc);

  // G1/G2: 128x128 dbuf, 2 blocks/CU (512 blocks = 1 full CU-wave x2)
  gemm_db<<<dim3(512), 256, 0, stream>>>(obsB, W1t, b1, h1, 1024, 512, 0, 8);
  gemm_db<<<dim3(512), 256, 0, stream>>>(h1, W2t, b2, h2, 1024, 1024, 0, 8);

  // G3 fused: 24x64 = 1536 blocks (3 full CU-waves)
  gemm_fused<<<dim3(1536), 256, 0, stream>>>(h2, Wbigt, biasc, masks, actions,
                                             partials, critic, 1024);

  finalize3<<<2048, 256, 0, stream>>>(partials, critic, Wc2, bc2, out);
}

// Round 8
// 134.167 us; speedup vs baseline: 1.1022x; 1.0590x over previous
//
#include <hip/hip_runtime.h>
#include <hip/hip_bf16.h>
#include <stdint.h>

// ---------------------------------------------------------------------------
// MaskedPolicy: obs->MLP->heads (masked log-softmax, gather, entropy) + critic
// B=8192 OBS=512 HID=1024 N*SUM=2560 (+512 critic cols = 3072 fused GEMM3)
// G1/G2: 128x128 dbuf GEMM (2 blocks/CU). G3: fused epilogue with HOISTED
// mask/action loads (issue all 80 loads, then consume -> 1 latency exposure).
// ---------------------------------------------------------------------------

typedef __bf16 v8bf __attribute__((ext_vector_type(8)));
typedef float  v4f  __attribute__((ext_vector_type(4)));

__device__ __forceinline__ void load_lds16(const void* g, void* l) {
  auto gp = (const __attribute__((address_space(1))) char*)(uintptr_t)g;
  auto lp = (__attribute__((address_space(3))) char*)(uintptr_t)l;
  __builtin_amdgcn_global_load_lds(gp, lp, 16, 0, 0);
}

#define BARRIER __builtin_amdgcn_s_barrier()
#define SCHEDB  __builtin_amdgcn_sched_barrier(0)
#define WAIT_LGKM0 do { asm volatile("s_waitcnt lgkmcnt(0)" ::: "memory"); SCHEDB; } while (0)
#define WAIT_LGKM8 do { asm volatile("s_waitcnt lgkmcnt(8)" ::: "memory"); SCHEDB; } while (0)
#define WAIT_VM8   do { asm volatile("s_waitcnt vmcnt(8)" ::: "memory"); SCHEDB; } while (0)
#define WAIT_VM0   do { asm volatile("s_waitcnt vmcnt(0)" ::: "memory"); SCHEDB; } while (0)

// ---------------------------------------------------------------------------
// prep mega-kernel (unchanged, verified)
// ---------------------------------------------------------------------------

__global__ __launch_bounds__(256)
void prep_kernel(const float* __restrict__ obs,
                 const float* __restrict__ W1, const float* __restrict__ W2,
                 const float* __restrict__ headsW, const float* __restrict__ Wc1,
                 const float* __restrict__ headsb, const float* __restrict__ bc1,
                 int4* __restrict__ obsB,
                 __hip_bfloat16* __restrict__ W1t, __hip_bfloat16* __restrict__ W2t,
                 __hip_bfloat16* __restrict__ Wbigt, float* __restrict__ biasc) {
  const int b = blockIdx.x;
  const int tid = threadIdx.x;
  if (b < 4608) {
    const float* in; __hip_bfloat16* outp; int R, C, bxx, byy;
    if (b < 512)       { in = W1;  outp = W1t; R = 512;  C = 1024; bxx = b % 32; byy = b / 32; }
    else if (b < 1536) { int i = b - 512;  in = W2;  outp = W2t; R = 1024; C = 1024; bxx = i % 32; byy = i / 32; }
    else if (b < 4096) { int i = b - 1536; int bz = i / 320; i %= 320;
                         in = headsW + (size_t)bz * 1024 * 320;
                         outp = Wbigt + (size_t)bz * 320 * 1024;
                         R = 1024; C = 320; bxx = i % 10; byy = i / 10; }
    else               { int i = b - 4096; in = Wc1; outp = Wbigt + 2560 * 1024;
                         R = 1024; C = 512; bxx = i % 16; byy = i / 16; }
    __shared__ float t[32][33];
    const int x = tid & 31, y = tid >> 5;
    const int bx0 = bxx * 32, by0 = byy * 32;
#pragma unroll
    for (int i = 0; i < 32; i += 8)
      t[y + i][x] = in[(size_t)(by0 + y + i) * C + bx0 + x];
    __syncthreads();
#pragma unroll
    for (int i = 0; i < 32; i += 8)
      outp[(size_t)(bx0 + y + i) * R + by0 + x] = __float2bfloat16(t[x][y + i]);
  } else if (b < 6656) {
    const int i = (b - 4608) * 256 + tid;   // < 524288
    const float4 x = ((const float4*)obs)[i * 2], y = ((const float4*)obs)[i * 2 + 1];
    union { __hip_bfloat16 h[8]; int4 v; } u;
    u.h[0] = __float2bfloat16(x.x); u.h[1] = __float2bfloat16(x.y);
    u.h[2] = __float2bfloat16(x.z); u.h[3] = __float2bfloat16(x.w);
    u.h[4] = __float2bfloat16(y.x); u.h[5] = __float2bfloat16(y.y);
    u.h[6] = __float2bfloat16(y.z); u.h[7] = __float2bfloat16(y.w);
    obsB[i] = u.v;
  } else {
    const int i = (b - 6656) * 256 + tid;
    if (i < 2560) biasc[i] = headsb[i];
    else if (i < 3072) biasc[i] = bc1[i - 2560];
  }
}

// ---------------------------------------------------------------------------
// shared swizzle helpers (verified: pass + 0 bank conflicts)
// ---------------------------------------------------------------------------

__device__ __forceinline__ void decode_chunk(int o, int& r, int& cb) {
  const int L = o ^ (((o >> 9) & 1) << 5);
  r  = ((L >> 10) << 4) | ((L >> 6) & 15);
  cb = ((L >> 4) & 3) << 4;
}

// ---------------------------------------------------------------------------
// G1/G2 GEMM: 128x128, BK=64, 4 waves, dbuf, 2 blocks/CU (round-4, verified)
// ---------------------------------------------------------------------------

__global__ __launch_bounds__(256, 2)
void gemm_db(const __hip_bfloat16* __restrict__ A,
             const __hip_bfloat16* __restrict__ Bt,
             const float* __restrict__ bias,
             __hip_bfloat16* __restrict__ C,
             int N, int K, int relu_from, int gx) {
  __shared__ char smem[65536];

  const int tid  = threadIdx.x;
  const int lane = tid & 63;
  const int wave = tid >> 6;
  const int wr = wave >> 1, wc = wave & 1;
  const int lr = lane & 15, ls = lane >> 4;

  const int nwg = gridDim.x;
  const int q8 = nwg >> 3;
  const int id = (blockIdx.x & 7) * q8 + (blockIdx.x >> 3);
  const int bx = id % gx, by = id / gx;
  const int m0 = by * 128, n0 = bx * 128;

  int r0, c0, r1, c1;
  decode_chunk(tid * 16, r0, c0);
  decode_chunk(tid * 16 + 4096, r1, c1);

  const size_t K2 = (size_t)K * 2;
  const char* pA0 = (const char*)A  + (size_t)(m0 + r0) * K2 + c0;
  const char* pA1 = (const char*)A  + (size_t)(m0 + r1) * K2 + c1;
  const char* pB0 = (const char*)Bt + (size_t)(n0 + r0) * K2 + c0;
  const char* pB1 = (const char*)Bt + (size_t)(n0 + r1) * K2 + c1;

  char* const s0 = smem + (tid << 4);

  auto stage = [&](int buf) {
    char* d = s0 + (buf << 15);
    load_lds16(pA0,      d);
    load_lds16(pA1,      d + 4096);
    load_lds16(pA0 + 64, d + 8192);
    load_lds16(pA1 + 64, d + 12288);
    load_lds16(pB0,      d + 16384);
    load_lds16(pB1,      d + 20480);
    load_lds16(pB0 + 64, d + 24576);
    load_lds16(pB1 + 64, d + 28672);
    pA0 += 128; pA1 += 128; pB0 += 128; pB1 += 128;
  };

  const int laneOff = lr * 64 + ((ls * 16) ^ ((lr & 8) << 2));

  v4f acc[4][4] = {};

  auto tile = [&](int buf, bool doStage, auto gate) {
    const char* aB = smem + (buf << 15) + wr * 4096 + laneOff;
    const char* bB = smem + (buf << 15) + 16384 + wc * 4096 + laneOff;
    v8bf a0[4], b0[4], a1[4], b1[4];
#pragma unroll
    for (int m = 0; m < 4; ++m) a0[m] = *(const v8bf*)(aB + m * 1024);
#pragma unroll
    for (int n = 0; n < 4; ++n) b0[n] = *(const v8bf*)(bB + n * 1024);
#pragma unroll
    for (int m = 0; m < 4; ++m) a1[m] = *(const v8bf*)(aB + 8192 + m * 1024);
#pragma unroll
    for (int n = 0; n < 4; ++n) b1[n] = *(const v8bf*)(bB + 8192 + n * 1024);
    WAIT_LGKM8;
    __builtin_amdgcn_s_setprio(1);
#pragma unroll
    for (int m = 0; m < 4; ++m)
#pragma unroll
      for (int n = 0; n < 4; ++n)
        acc[m][n] = __builtin_amdgcn_mfma_f32_16x16x32_bf16(a0[m], b0[n], acc[m][n], 0, 0, 0);
    __builtin_amdgcn_s_setprio(0); SCHEDB;
    WAIT_LGKM0;
    BARRIER;
    if (doStage) stage(buf);
    __builtin_amdgcn_s_setprio(1);
#pragma unroll
    for (int m = 0; m < 4; ++m)
#pragma unroll
      for (int n = 0; n < 4; ++n)
        acc[m][n] = __builtin_amdgcn_mfma_f32_16x16x32_bf16(a1[m], b1[n], acc[m][n], 0, 0, 0);
    __builtin_amdgcn_s_setprio(0); SCHEDB;
    gate();
    BARRIER;
  };

  stage(0);
  stage(1);
  WAIT_VM8;
  BARRIER; SCHEDB;

  const int NT = K >> 6;
  int t = 0;
  for (; t < NT - 2; ++t)
    tile(t & 1, true, [] { WAIT_VM8; });
  tile(t & 1, false, [] { WAIT_VM0; }); ++t;
  tile(t & 1, false, [] {});

  const int colb = n0 + wc * 64 + lr;
  const int rowb = m0 + wr * 64 + ls * 4;
#pragma unroll
  for (int n = 0; n < 4; ++n) {
    const int col = colb + n * 16;
    const float bv = bias[col];
    const bool rl = (col >= relu_from);
#pragma unroll
    for (int m = 0; m < 4; ++m) {
      const int rbase = rowb + m * 16;
#pragma unroll
      for (int j = 0; j < 4; ++j) {
        float v = acc[m][n][j] + bv;
        if (rl) v = fmaxf(v, 0.0f);
        C[(size_t)(rbase + j) * N + col] = __float2bfloat16(v);
      }
    }
  }
}

// ---------------------------------------------------------------------------
// G3 fused: GEMM core + masked log-softmax epilogue. v2: all mask/action
// loads hoisted into registers (80 loads in flight -> one latency exposure).
// ---------------------------------------------------------------------------

__global__ __launch_bounds__(256, 2)
void gemm_fused(const __hip_bfloat16* __restrict__ A,
                const __hip_bfloat16* __restrict__ Bt,
                const float* __restrict__ bias,
                const int* __restrict__ masks,
                const int* __restrict__ actions,
                float2* __restrict__ partials,
                __hip_bfloat16* __restrict__ critic,
                int K) {
  __shared__ char smem[65536];

  const int tid  = threadIdx.x;
  const int lane = tid & 63;
  const int wave = tid >> 6;
  const int wr = wave >> 1, wc = wave & 1;
  const int lr = lane & 15, ls = lane >> 4;

  const int nwg = gridDim.x;
  const int q8 = nwg >> 3;
  const int id = (blockIdx.x & 7) * q8 + (blockIdx.x >> 3);
  const int bx = id % 24, by = id / 24;
  const int m0 = by * 128, n0 = bx * 128;

  int r0, c0, r1, c1;
  decode_chunk(tid * 16, r0, c0);
  decode_chunk(tid * 16 + 4096, r1, c1);

  const size_t K2 = (size_t)K * 2;
  const char* pA0 = (const char*)A  + (size_t)(m0 + r0) * K2 + c0;
  const char* pA1 = (const char*)A  + (size_t)(m0 + r1) * K2 + c1;
  const char* pB0 = (const char*)Bt + (size_t)(n0 + r0) * K2 + c0;
  const char* pB1 = (const char*)Bt + (size_t)(n0 + r1) * K2 + c1;

  char* const s0 = smem + (tid << 4);

  auto stage = [&](int buf) {
    char* d = s0 + (buf << 15);
    load_lds16(pA0,      d);
    load_lds16(pA1,      d + 4096);
    load_lds16(pA0 + 64, d + 8192);
    load_lds16(pA1 + 64, d + 12288);
    load_lds16(pB0,      d + 16384);
    load_lds16(pB1,      d + 20480);
    load_lds16(pB0 + 64, d + 24576);
    load_lds16(pB1 + 64, d + 28672);
    pA0 += 128; pA1 += 128; pB0 += 128; pB1 += 128;
  };

  const int laneOff = lr * 64 + ((ls * 16) ^ ((lr & 8) << 2));

  v4f acc[4][4] = {};

  auto tile = [&](int buf, bool doStage, auto gate) {
    const char* aB = smem + (buf << 15) + wr * 4096 + laneOff;
    const char* bB = smem + (buf << 15) + 16384 + wc * 4096 + laneOff;
    v8bf a0[4], b0[4], a1[4], b1[4];
#pragma unroll
    for (int m = 0; m < 4; ++m) a0[m] = *(const v8bf*)(aB + m * 1024);
#pragma unroll
    for (int n = 0; n < 4; ++n) b0[n] = *(const v8bf*)(bB + n * 1024);
#pragma unroll
    for (int m = 0; m < 4; ++m) a1[m] = *(const v8bf*)(aB + 8192 + m * 1024);
#pragma unroll
    for (int n = 0; n < 4; ++n) b1[n] = *(const v8bf*)(bB + 8192 + n * 1024);
    WAIT_LGKM8;
    __builtin_amdgcn_s_setprio(1);
#pragma unroll
    for (int m = 0; m < 4; ++m)
#pragma unroll
      for (int n = 0; n < 4; ++n)
        acc[m][n] = __builtin_amdgcn_mfma_f32_16x16x32_bf16(a0[m], b0[n], acc[m][n], 0, 0, 0);
    __builtin_amdgcn_s_setprio(0); SCHEDB;
    WAIT_LGKM0;
    BARRIER;
    if (doStage) stage(buf);
    __builtin_amdgcn_s_setprio(1);
#pragma unroll
    for (int m = 0; m < 4; ++m)
#pragma unroll
      for (int n = 0; n < 4; ++n)
        acc[m][n] = __builtin_amdgcn_mfma_f32_16x16x32_bf16(a1[m], b1[n], acc[m][n], 0, 0, 0);
    __builtin_amdgcn_s_setprio(0); SCHEDB;
    gate();
    BARRIER;
  };

  stage(0);
  stage(1);
  WAIT_VM8;
  BARRIER; SCHEDB;

  const int NT = K >> 6;
  int t = 0;
  for (; t < NT - 2; ++t)
    tile(t & 1, true, [] { WAIT_VM8; });
  tile(t & 1, false, [] { WAIT_VM0; }); ++t;
  tile(t & 1, false, [] {});

  const int rowb = m0 + wr * 64 + ls * 4;

  if (bx < 20) {
    // ---- fused masked log-softmax; all loads hoisted before any consume ----
    const int seg = bx * 2 + wc;

    int mkv[4][4][4];   // [m][j][n] — fully unrolled, static indexing
    int actv[4][4];
#pragma unroll
    for (int m = 0; m < 4; ++m)
#pragma unroll
      for (int j = 0; j < 4; ++j) {
        const int row = rowb + m * 16 + j;
        const int* mrow = masks + (size_t)row * 2560 + seg * 64 + lr;
#pragma unroll
        for (int n = 0; n < 4; ++n) mkv[m][j][n] = mrow[n * 16];
        actv[m][j] = actions[row * 40 + seg];
      }

    float bv[4];
#pragma unroll
    for (int n = 0; n < 4; ++n) bv[n] = bias[n0 + wc * 64 + n * 16 + lr];

#pragma unroll
    for (int m = 0; m < 4; ++m) {
#pragma unroll
      for (int j = 0; j < 4; ++j) {
        const int row = rowb + m * 16 + j;
        float v[4];
#pragma unroll
        for (int n = 0; n < 4; ++n)
          v[n] = mkv[m][j][n] ? (acc[m][n][j] + bv[n]) : -1.0e9f;
        float mx = fmaxf(fmaxf(v[0], v[1]), fmaxf(v[2], v[3]));
#pragma unroll
        for (int o = 1; o < 16; o <<= 1) mx = fmaxf(mx, __shfl_xor(mx, o));
        float s = 0.f, sv = 0.f;
#pragma unroll
        for (int n = 0; n < 4; ++n) {
          const float e = __expf(v[n] - mx);
          s += e; sv += e * v[n];
        }
#pragma unroll
        for (int o = 1; o < 16; o <<= 1) { s += __shfl_xor(s, o); sv += __shfl_xor(sv, o); }
        const float logZ = __logf(s) + mx;
        const int act = actv[m][j];
        float va_loc = v[0];
        va_loc = (((act >> 4) & 3) == 1) ? v[1] : va_loc;
        va_loc = (((act >> 4) & 3) == 2) ? v[2] : va_loc;
        va_loc = (((act >> 4) & 3) == 3) ? v[3] : va_loc;
        const float va = __shfl(va_loc, (lane & 48) | (act & 15));
        float lp, ent;
        if ((unsigned)act < 64u) { lp = va - logZ; ent = logZ - sv / s; }
        else                     { lp = -1000.0f;  ent = 0.0f; }
        if (lr == 0) partials[row * 40 + seg] = make_float2(lp, ent);
      }
    }
  } else {
    // ---- critic columns: relu + bf16 store to compact [8192][512] ----
    const int cb = (bx - 20) * 128 + wc * 64;
#pragma unroll
    for (int n = 0; n < 4; ++n) {
      const int col = cb + n * 16 + lr;
      const float bvv = bias[2560 + col];
#pragma unroll
      for (int m = 0; m < 4; ++m) {
        const int rbase = rowb + m * 16;
#pragma unroll
        for (int j = 0; j < 4; ++j)
          critic[(size_t)(rbase + j) * 512 + col] =
              __float2bfloat16(fmaxf(acc[m][n][j] + bvv, 0.0f));
      }
    }
  }
}

// ---------------------------------------------------------------------------
// finalize v3: tiny reduce — 80 f32 partials + critic dot per row
// ---------------------------------------------------------------------------

__global__ __launch_bounds__(256)
void finalize3(const float2* __restrict__ partials,
               const __hip_bfloat16* __restrict__ critic,
               const float* __restrict__ Wc2,
               const float* __restrict__ bc2,
               float* __restrict__ out) {
  const int lane = threadIdx.x & 63;
  const int r = blockIdx.x * 4 + (threadIdx.x >> 6);

  float lp = 0.f, ent = 0.f;
  if (lane < 40) {
    const float2 t = partials[r * 40 + lane];
    lp = t.x; ent = t.y;
  }
#pragma unroll
  for (int o = 32; o > 0; o >>= 1) { lp += __shfl_xor(lp, o); ent += __shfl_xor(ent, o); }

  union { int4 q; __hip_bfloat16 h[8]; } c;
  c.q = *(const int4*)(critic + (size_t)r * 512 + lane * 8);
  const float4 w0 = *(const float4*)(Wc2 + lane * 8);
  const float4 w1 = *(const float4*)(Wc2 + lane * 8 + 4);
  float acc = __bfloat162float(c.h[0]) * w0.x + __bfloat162float(c.h[1]) * w0.y +
              __bfloat162float(c.h[2]) * w0.z + __bfloat162float(c.h[3]) * w0.w +
              __bfloat162float(c.h[4]) * w1.x + __bfloat162float(c.h[5]) * w1.y +
              __bfloat162float(c.h[6]) * w1.z + __bfloat162float(c.h[7]) * w1.w;
#pragma unroll
  for (int o = 32; o > 0; o >>= 1) acc += __shfl_xor(acc, o);

  if (lane == 0) {
    out[r]         = lp;
    out[8192 + r]  = ent;
    out[16384 + r] = acc + bc2[0];
  }
}

// ---------------------------------------------------------------------------

extern "C" void kernel_launch(void* const* d_in, const int* in_sizes, int n_in,
                              void* d_out, int out_size, void* d_ws, size_t ws_size,
                              hipStream_t stream) {
  const float* obs    = (const float*)d_in[0];
  const int*   actions= (const int*)d_in[1];
  const int*   masks  = (const int*)d_in[2];
  const float* W1     = (const float*)d_in[3];
  const float* b1     = (const float*)d_in[4];
  const float* W2     = (const float*)d_in[5];
  const float* b2     = (const float*)d_in[6];
  const float* headsW = (const float*)d_in[7];
  const float* headsb = (const float*)d_in[8];
  const float* Wc1    = (const float*)d_in[9];
  const float* bc1    = (const float*)d_in[10];
  const float* Wc2    = (const float*)d_in[11];
  const float* bc2    = (const float*)d_in[12];
  float* out = (float*)d_out;

  char* ws = (char*)d_ws;
  __hip_bfloat16* obsB  = (__hip_bfloat16*)(ws);              // 8192*512*2   = 8388608
  __hip_bfloat16* W1t   = (__hip_bfloat16*)(ws + 8388608);    // 1024*512*2   = 1048576
  __hip_bfloat16* W2t   = (__hip_bfloat16*)(ws + 9437184);    // 1024*1024*2  = 2097152
  __hip_bfloat16* Wbigt = (__hip_bfloat16*)(ws + 11534336);   // 3072*1024*2  = 6291456
  float*          biasc = (float*)(ws + 17825792);            // 3072*4       = 12288
  __hip_bfloat16* h1    = (__hip_bfloat16*)(ws + 17838080);   // 8192*1024*2  = 16777216
  __hip_bfloat16* h2    = (__hip_bfloat16*)(ws + 34615296);   // 8192*1024*2  = 16777216
  float2*      partials = (float2*)(ws + 51392512);           // 8192*40*8    = 2621440
  __hip_bfloat16* critic= (__hip_bfloat16*)(ws + 54013952);   // 8192*512*2   = 8388608

  prep_kernel<<<6668, 256, 0, stream>>>(obs, W1, W2, headsW, Wc1, headsb, bc1,
                                        (int4*)obsB, W1t, W2t, Wbigt, biasc);

  // G1/G2: 128x128 dbuf, 2 blocks/CU (512 blocks = 1 full CU-wave x2)
  gemm_db<<<dim3(512), 256, 0, stream>>>(obsB, W1t, b1, h1, 1024, 512, 0, 8);
  gemm_db<<<dim3(512), 256, 0, stream>>>(h1, W2t, b2, h2, 1024, 1024, 0, 8);

  // G3 fused: 24x64 = 1536 blocks (3 full CU-waves)
  gemm_fused<<<dim3(1536), 256, 0, stream>>>(h2, Wbigt, biasc, masks, actions,
                                             partials, critic, 1024);

  finalize3<<<2048, 256, 0, stream>>>(partials, critic, Wc2, bc2, out);
}